// Round 1
// baseline (665.278 us; speedup 1.0000x reference)
//
#include <hip/hip_runtime.h>
#include <hip/hip_bf16.h>

typedef __attribute__((ext_vector_type(8))) short short8;
typedef __attribute__((ext_vector_type(4))) float f32x4;

__device__ inline short f2bf(float f) {
    union { float f; unsigned u; } v; v.f = f;
    unsigned r = v.u + 0x7fffu + ((v.u >> 16) & 1u);
    return (short)(r >> 16);
}

// ---------------------------------------------------------------------------
// K1: qkv = x @ W_qkv   (M=8192, K=512, N=1536), scatter to
//     q[b*8+h][n][d] bf16, k[b*8+h][n][d] bf16, vT[b*8+h][d][n] bf16
// ---------------------------------------------------------------------------
__global__ __launch_bounds__(256) void qkv_gemm(
    const float* __restrict__ x, const float* __restrict__ W,
    short* __restrict__ q, short* __restrict__ k, short* __restrict__ vt)
{
    __shared__ short sA[64][40];   // A[m][k], pad keeps b128 reads ~conflict-free
    __shared__ short sBt[64][40];  // B^T[n][k]

    const int tid  = threadIdx.x;
    const int wv   = tid >> 6, lane = tid & 63;
    const int quad = lane >> 4, l16 = lane & 15;
    const int m0 = blockIdx.x * 64, n0 = blockIdx.y * 64;

    f32x4 acc[4];
#pragma unroll
    for (int i = 0; i < 4; i++) acc[i] = (f32x4){0.f, 0.f, 0.f, 0.f};

    const int ar = tid >> 2, ac = (tid & 3) * 8;   // A stage: 64 rows x 32 cols
    const int bk = tid >> 3, bn = (tid & 7) * 8;   // B stage: 32 rows x 64 cols

    for (int ks = 0; ks < 16; ks++) {
        const int k0 = ks * 32;
        const float* xp = x + (size_t)(m0 + ar) * 512 + k0 + ac;
        float4 a0 = *(const float4*)xp;
        float4 a1 = *(const float4*)(xp + 4);
        const float* wp = W + (size_t)(k0 + bk) * 1536 + n0 + bn;
        float4 b0 = *(const float4*)wp;
        float4 b1 = *(const float4*)(wp + 4);

        __syncthreads();
        short8 av = { f2bf(a0.x), f2bf(a0.y), f2bf(a0.z), f2bf(a0.w),
                      f2bf(a1.x), f2bf(a1.y), f2bf(a1.z), f2bf(a1.w) };
        *(short8*)&sA[ar][ac] = av;
        sBt[bn + 0][bk] = f2bf(b0.x); sBt[bn + 1][bk] = f2bf(b0.y);
        sBt[bn + 2][bk] = f2bf(b0.z); sBt[bn + 3][bk] = f2bf(b0.w);
        sBt[bn + 4][bk] = f2bf(b1.x); sBt[bn + 5][bk] = f2bf(b1.y);
        sBt[bn + 6][bk] = f2bf(b1.z); sBt[bn + 7][bk] = f2bf(b1.w);
        __syncthreads();

        short8 af = *(const short8*)&sA[wv * 16 + l16][quad * 8];
#pragma unroll
        for (int ns = 0; ns < 4; ns++) {
            short8 bf = *(const short8*)&sBt[ns * 16 + l16][quad * 8];
            acc[ns] = __builtin_amdgcn_mfma_f32_16x16x32_bf16(af, bf, acc[ns], 0, 0, 0);
        }
    }

#pragma unroll
    for (int ns = 0; ns < 4; ns++) {
        const int gc  = n0 + ns * 16 + l16;
        const int sec = gc >> 9;          // 0=q 1=k 2=v
        const int cc  = gc & 511;
        const int h = cc >> 6, d = cc & 63;
#pragma unroll
        for (int i = 0; i < 4; i++) {
            const int gm = m0 + wv * 16 + quad * 4 + i;
            const int b = gm >> 10, n = gm & 1023;
            const int bh = b * 8 + h;
            short val = f2bf(acc[ns][i]);
            if (sec == 0)      q[((size_t)(bh * 1024 + n)) * 64 + d] = val;
            else if (sec == 1) k[((size_t)(bh * 1024 + n)) * 64 + d] = val;
            else               vt[((size_t)(bh * 64 + d)) * 1024 + n] = val;
        }
    }
}

// ---------------------------------------------------------------------------
// K2: attention. One block = one (b,h) x 16 query rows. 4 waves x 256 cols.
// Score stripe lives in 64 acc VGPRs/lane; 3 register passes; P->LDS->PV.
// ---------------------------------------------------------------------------
__global__ __launch_bounds__(256) void attn_k(
    const short* __restrict__ q, const short* __restrict__ kk,
    const short* __restrict__ vt, const float* __restrict__ spd,
    const float* __restrict__ hm, short* __restrict__ o)
{
    __shared__ short sP[16][1032];     // 33 KB, stride -> 2-way (free) b128 reads
    __shared__ float sred[2][4][16];
    __shared__ float ratio_s[16], rmax_s[16], rinv_s[16];

    const int tid  = threadIdx.x;
    const int wv   = tid >> 6, lane = tid & 63;
    const int quad = lane >> 4, l16 = lane & 15;
    const int qt = blockIdx.x, bh = blockIdx.y;
    const int b = bh >> 3, h = bh & 7;
    const int q0 = qt * 16;

    // Q fragments (A-layout): m = l16, k = quad*8+j (+32 for second step)
    const short* qb = q + ((size_t)bh * 1024 + q0 + l16) * 64;
    short8 aq0 = *(const short8*)(qb + quad * 8);
    short8 aq1 = *(const short8*)(qb + 32 + quad * 8);

    f32x4 acc[16];
#pragma unroll
    for (int t = 0; t < 16; t++) acc[t] = (f32x4){0.f, 0.f, 0.f, 0.f};

    const short* kbh = kk + (size_t)bh * 1024 * 64;
#pragma unroll 4
    for (int t = 0; t < 16; t++) {
        const short* kb = kbh + (size_t)(wv * 256 + t * 16 + l16) * 64;
        short8 b0 = *(const short8*)(kb + quad * 8);
        short8 b1 = *(const short8*)(kb + 32 + quad * 8);
        acc[t] = __builtin_amdgcn_mfma_f32_16x16x32_bf16(aq0, b0, acc[t], 0, 0, 0);
        acc[t] = __builtin_amdgcn_mfma_f32_16x16x32_bf16(aq1, b1, acc[t], 0, 0, 0);
    }
#pragma unroll
    for (int t = 0; t < 16; t++)
#pragma unroll
        for (int i = 0; i < 4; i++) acc[t][i] *= 0.125f;   // SCALE = DH^-0.5

    const float* spdb = spd + ((size_t)b * 1024 + q0) * 1024;

    // ---- pass 1: row norms of dots and dots*spd ----
    float dn[4] = {0.f, 0.f, 0.f, 0.f}, pn[4] = {0.f, 0.f, 0.f, 0.f};
#pragma unroll 4
    for (int t = 0; t < 16; t++) {
        const int col = wv * 256 + t * 16 + l16;
#pragma unroll
        for (int i = 0; i < 4; i++) {
            float s  = acc[t][i];
            float sv = spdb[(quad * 4 + i) * 1024 + col];
            dn[i] += s * s;
            pn[i] += s * s * sv * sv;
        }
    }
#pragma unroll
    for (int m = 1; m < 16; m <<= 1)
#pragma unroll
        for (int i = 0; i < 4; i++) {
            dn[i] += __shfl_xor(dn[i], m, 64);
            pn[i] += __shfl_xor(pn[i], m, 64);
        }
    if (l16 == 0)
#pragma unroll
        for (int i = 0; i < 4; i++) {
            sred[0][wv][quad * 4 + i] = dn[i];
            sred[1][wv][quad * 4 + i] = pn[i];
        }
    __syncthreads();
    if (tid < 16) {
        float d = 0.f, p = 0.f;
        for (int w2 = 0; w2 < 4; w2++) { d += sred[0][w2][tid]; p += sred[1][w2][tid]; }
        ratio_s[tid] = sqrtf(d) / fmaxf(sqrtf(p), 1e-12f);
    }
    __syncthreads();

    // ---- pass 2: logits (overwrite acc) + row max ----
    float mx[4] = {-1e30f, -1e30f, -1e30f, -1e30f};
#pragma unroll 4
    for (int t = 0; t < 16; t++) {
        const int col = wv * 256 + t * 16 + l16;
#pragma unroll
        for (int i = 0; i < 4; i++) {
            float s  = acc[t][i];
            float sv = spdb[(quad * 4 + i) * 1024 + col];
            float l  = s + s * sv * ratio_s[quad * 4 + i];
            acc[t][i] = l;
            mx[i] = fmaxf(mx[i], l);
        }
    }
#pragma unroll
    for (int m = 1; m < 16; m <<= 1)
#pragma unroll
        for (int i = 0; i < 4; i++) mx[i] = fmaxf(mx[i], __shfl_xor(mx[i], m, 64));
    if (l16 == 0)
#pragma unroll
        for (int i = 0; i < 4; i++) sred[0][wv][quad * 4 + i] = mx[i];
    __syncthreads();
    if (tid < 16) {
        float m2 = -1e30f;
        for (int w2 = 0; w2 < 4; w2++) m2 = fmaxf(m2, sred[0][w2][tid]);
        rmax_s[tid] = m2;
    }
    __syncthreads();

    // ---- pass 3: exp (overwrite acc) + row sum ----
    float rs[4] = {0.f, 0.f, 0.f, 0.f};
#pragma unroll
    for (int t = 0; t < 16; t++)
#pragma unroll
        for (int i = 0; i < 4; i++) {
            float p = __expf(acc[t][i] - rmax_s[quad * 4 + i]);
            acc[t][i] = p;
            rs[i] += p;
        }
#pragma unroll
    for (int m = 1; m < 16; m <<= 1)
#pragma unroll
        for (int i = 0; i < 4; i++) rs[i] += __shfl_xor(rs[i], m, 64);
    if (l16 == 0)
#pragma unroll
        for (int i = 0; i < 4; i++) sred[0][wv][quad * 4 + i] = rs[i];
    __syncthreads();
    if (tid < 16) {
        float s = 0.f;
        for (int w2 = 0; w2 < 4; w2++) s += sred[0][w2][tid];
        float hsum = 0.f;
        for (int j = 0; j < 8; j++) hsum += hm[j];
        rinv_s[tid] = (hm[h] * 8.0f / hsum) / s;   // softmax denom + head-mask scale
    }
    __syncthreads();

    // ---- P (scaled) -> LDS in row-major, bf16 ----
#pragma unroll
    for (int t = 0; t < 16; t++) {
        const int col = wv * 256 + t * 16 + l16;
#pragma unroll
        for (int i = 0; i < 4; i++)
            sP[quad * 4 + i][col] = f2bf(acc[t][i] * rinv_s[quad * 4 + i]);
    }
    __syncthreads();

    // ---- O = P @ V : wave wv does v-dims [wv*16, wv*16+16), K-loop over 1024
    f32x4 oacc = (f32x4){0.f, 0.f, 0.f, 0.f};
    const short* vb = vt + ((size_t)bh * 64 + wv * 16 + l16) * 1024;
#pragma unroll 4
    for (int kkk = 0; kkk < 32; kkk++) {
        short8 pa = *(const short8*)&sP[l16][kkk * 32 + quad * 8];
        short8 vf = *(const short8*)(vb + kkk * 32 + quad * 8);
        oacc = __builtin_amdgcn_mfma_f32_16x16x32_bf16(pa, vf, oacc, 0, 0, 0);
    }
#pragma unroll
    for (int i = 0; i < 4; i++)
        o[((size_t)(b * 1024 + q0 + quad * 4 + i)) * 512 + h * 64 + wv * 16 + l16]
            = f2bf(oacc[i]);
}

// ---------------------------------------------------------------------------
// K3: out = O @ W_out + b_out   (M=8192, K=512, N=512), fp32 output
// ---------------------------------------------------------------------------
__global__ __launch_bounds__(256) void out_gemm(
    const short* __restrict__ o, const float* __restrict__ W,
    const float* __restrict__ bias, float* __restrict__ out)
{
    __shared__ short sA[64][40];
    __shared__ short sBt[64][40];

    const int tid  = threadIdx.x;
    const int wv   = tid >> 6, lane = tid & 63;
    const int quad = lane >> 4, l16 = lane & 15;
    const int m0 = blockIdx.x * 64, n0 = blockIdx.y * 64;

    f32x4 acc[4];
#pragma unroll
    for (int i = 0; i < 4; i++) acc[i] = (f32x4){0.f, 0.f, 0.f, 0.f};

    const int ar = tid >> 2, ac = (tid & 3) * 8;
    const int bk = tid >> 3, bn = (tid & 7) * 8;

    for (int ks = 0; ks < 16; ks++) {
        const int k0 = ks * 32;
        short8 av = *(const short8*)(o + (size_t)(m0 + ar) * 512 + k0 + ac);
        const float* wp = W + (size_t)(k0 + bk) * 512 + n0 + bn;
        float4 b0 = *(const float4*)wp;
        float4 b1 = *(const float4*)(wp + 4);

        __syncthreads();
        *(short8*)&sA[ar][ac] = av;
        sBt[bn + 0][bk] = f2bf(b0.x); sBt[bn + 1][bk] = f2bf(b0.y);
        sBt[bn + 2][bk] = f2bf(b0.z); sBt[bn + 3][bk] = f2bf(b0.w);
        sBt[bn + 4][bk] = f2bf(b1.x); sBt[bn + 5][bk] = f2bf(b1.y);
        sBt[bn + 6][bk] = f2bf(b1.z); sBt[bn + 7][bk] = f2bf(b1.w);
        __syncthreads();

        short8 af = *(const short8*)&sA[wv * 16 + l16][quad * 8];
#pragma unroll
        for (int ns = 0; ns < 4; ns++) {
            short8 bf = *(const short8*)&sBt[ns * 16 + l16][quad * 8];
            acc[ns] = __builtin_amdgcn_mfma_f32_16x16x32_bf16(af, bf, acc[ns], 0, 0, 0);
        }
    }

#pragma unroll
    for (int ns = 0; ns < 4; ns++) {
        const int gc = n0 + ns * 16 + l16;
        const float bv = bias[gc];
#pragma unroll
        for (int i = 0; i < 4; i++) {
            const int gm = m0 + wv * 16 + quad * 4 + i;
            out[(size_t)gm * 512 + gc] = acc[ns][i] + bv;
        }
    }
}

// ---------------------------------------------------------------------------
extern "C" void kernel_launch(void* const* d_in, const int* in_sizes, int n_in,
                              void* d_out, int out_size, void* d_ws, size_t ws_size,
                              hipStream_t stream) {
    const float* x    = (const float*)d_in[0];
    const float* spd  = (const float*)d_in[1];
    const float* hm   = (const float*)d_in[2];
    const float* Wqkv = (const float*)d_in[3];
    const float* Wout = (const float*)d_in[4];
    const float* bout = (const float*)d_in[5];
    float* out = (float*)d_out;

    char* ws = (char*)d_ws;
    short* qw  = (short*)(ws);                     // 8 MB  [bh][n][d] bf16
    short* kw  = (short*)(ws + ((size_t)8  << 20)); // 8 MB  [bh][n][d] bf16
    short* vtw = (short*)(ws + ((size_t)16 << 20)); // 8 MB  [bh][d][n] bf16
    short* ow  = (short*)(ws + ((size_t)24 << 20)); // 8 MB  [b][n][h*64+d] bf16

    qkv_gemm<<<dim3(128, 24), 256, 0, stream>>>(x, Wqkv, qw, kw, vtw);
    attn_k  <<<dim3(64, 64),  256, 0, stream>>>(qw, kw, vtw, spd, hm, ow);
    out_gemm<<<dim3(128, 8),  256, 0, stream>>>(ow, Wout, bout, out);
}

// Round 2
// 333.031 us; speedup vs baseline: 1.9976x; 1.9976x over previous
//
#include <hip/hip_runtime.h>
#include <hip/hip_bf16.h>

typedef __attribute__((ext_vector_type(8))) short short8;
typedef __attribute__((ext_vector_type(4))) float f32x4;

__device__ inline short f2bf(float f) {
    union { float f; unsigned u; } v; v.f = f;
    unsigned r = v.u + 0x7fffu + ((v.u >> 16) & 1u);
    return (short)(r >> 16);
}

// ---------------------------------------------------------------------------
// K1: qkv = x @ W_qkv   (M=8192, K=512, N=1536), scatter to
//     q[b*8+h][n][d] bf16, k[b*8+h][n][d] bf16, vT[b*8+h][d][n] bf16
// ---------------------------------------------------------------------------
__global__ __launch_bounds__(256) void qkv_gemm(
    const float* __restrict__ x, const float* __restrict__ W,
    short* __restrict__ q, short* __restrict__ k, short* __restrict__ vt)
{
    __shared__ short sA[64][40];   // A[m][k], pad keeps b128 reads ~conflict-free
    __shared__ short sBt[64][40];  // B^T[n][k]

    const int tid  = threadIdx.x;
    const int wv   = tid >> 6, lane = tid & 63;
    const int quad = lane >> 4, l16 = lane & 15;
    const int m0 = blockIdx.x * 64, n0 = blockIdx.y * 64;

    f32x4 acc[4];
#pragma unroll
    for (int i = 0; i < 4; i++) acc[i] = (f32x4){0.f, 0.f, 0.f, 0.f};

    const int ar = tid >> 2, ac = (tid & 3) * 8;   // A stage: 64 rows x 32 cols
    const int bk = tid >> 3, bn = (tid & 7) * 8;   // B stage: 32 rows x 64 cols

    for (int ks = 0; ks < 16; ks++) {
        const int k0 = ks * 32;
        const float* xp = x + (size_t)(m0 + ar) * 512 + k0 + ac;
        float4 a0 = *(const float4*)xp;
        float4 a1 = *(const float4*)(xp + 4);
        const float* wp = W + (size_t)(k0 + bk) * 1536 + n0 + bn;
        float4 b0 = *(const float4*)wp;
        float4 b1 = *(const float4*)(wp + 4);

        __syncthreads();
        short8 av = { f2bf(a0.x), f2bf(a0.y), f2bf(a0.z), f2bf(a0.w),
                      f2bf(a1.x), f2bf(a1.y), f2bf(a1.z), f2bf(a1.w) };
        *(short8*)&sA[ar][ac] = av;
        sBt[bn + 0][bk] = f2bf(b0.x); sBt[bn + 1][bk] = f2bf(b0.y);
        sBt[bn + 2][bk] = f2bf(b0.z); sBt[bn + 3][bk] = f2bf(b0.w);
        sBt[bn + 4][bk] = f2bf(b1.x); sBt[bn + 5][bk] = f2bf(b1.y);
        sBt[bn + 6][bk] = f2bf(b1.z); sBt[bn + 7][bk] = f2bf(b1.w);
        __syncthreads();

        short8 af = *(const short8*)&sA[wv * 16 + l16][quad * 8];
#pragma unroll
        for (int ns = 0; ns < 4; ns++) {
            short8 bf = *(const short8*)&sBt[ns * 16 + l16][quad * 8];
            acc[ns] = __builtin_amdgcn_mfma_f32_16x16x32_bf16(af, bf, acc[ns], 0, 0, 0);
        }
    }

#pragma unroll
    for (int ns = 0; ns < 4; ns++) {
        const int gc  = n0 + ns * 16 + l16;
        const int sec = gc >> 9;          // 0=q 1=k 2=v
        const int cc  = gc & 511;
        const int h = cc >> 6, d = cc & 63;
#pragma unroll
        for (int i = 0; i < 4; i++) {
            const int gm = m0 + wv * 16 + quad * 4 + i;
            const int b = gm >> 10, n = gm & 1023;
            const int bh = b * 8 + h;
            short val = f2bf(acc[ns][i]);
            if (sec == 0)      q[((size_t)(bh * 1024 + n)) * 64 + d] = val;
            else if (sec == 1) k[((size_t)(bh * 1024 + n)) * 64 + d] = val;
            else               vt[((size_t)(bh * 64 + d)) * 1024 + n] = val;
        }
    }
}

// ---------------------------------------------------------------------------
// K2: attention. One block = one (b,h) x 16 query rows. 4 waves x 256 cols.
// Score stripe lives in 64 acc VGPRs/lane. ALL loops touching acc[] are
// FULLY unrolled — any runtime index would demote acc to scratch (R1: 1.3 GB
// of spill traffic, 8x slowdown).
// ---------------------------------------------------------------------------
__global__ __launch_bounds__(256) void attn_k(
    const short* __restrict__ q, const short* __restrict__ kk,
    const short* __restrict__ vt, const float* __restrict__ spd,
    const float* __restrict__ hm, short* __restrict__ o)
{
    __shared__ short sP[16][1032];     // 33 KB, stride -> 2-way (free) b128 reads
    __shared__ float sred[2][4][16];
    __shared__ float ratio_s[16], rmax_s[16], rinv_s[16];

    const int tid  = threadIdx.x;
    const int wv   = tid >> 6, lane = tid & 63;
    const int quad = lane >> 4, l16 = lane & 15;
    const int qt = blockIdx.x, bh = blockIdx.y;
    const int b = bh >> 3, h = bh & 7;
    const int q0 = qt * 16;

    // Q fragments (A-layout): m = l16, k = quad*8+j (+32 for second step)
    const short* qb = q + ((size_t)bh * 1024 + q0 + l16) * 64;
    short8 aq0 = *(const short8*)(qb + quad * 8);
    short8 aq1 = *(const short8*)(qb + 32 + quad * 8);

    f32x4 acc[16];
#pragma unroll
    for (int t = 0; t < 16; t++) acc[t] = (f32x4){0.f, 0.f, 0.f, 0.f};

    const short* kbh = kk + (size_t)bh * 1024 * 64;
#pragma unroll
    for (int t = 0; t < 16; t++) {
        const short* kb = kbh + (size_t)(wv * 256 + t * 16 + l16) * 64;
        short8 b0 = *(const short8*)(kb + quad * 8);
        short8 b1 = *(const short8*)(kb + 32 + quad * 8);
        acc[t] = __builtin_amdgcn_mfma_f32_16x16x32_bf16(aq0, b0, acc[t], 0, 0, 0);
        acc[t] = __builtin_amdgcn_mfma_f32_16x16x32_bf16(aq1, b1, acc[t], 0, 0, 0);
    }
#pragma unroll
    for (int t = 0; t < 16; t++)
#pragma unroll
        for (int i = 0; i < 4; i++) acc[t][i] *= 0.125f;   // SCALE = DH^-0.5

    const float* spdb = spd + ((size_t)b * 1024 + q0) * 1024;

    // ---- pass 1: row norms of dots and dots*spd ----
    float dn[4] = {0.f, 0.f, 0.f, 0.f}, pn[4] = {0.f, 0.f, 0.f, 0.f};
#pragma unroll
    for (int t = 0; t < 16; t++) {
        const int col = wv * 256 + t * 16 + l16;
#pragma unroll
        for (int i = 0; i < 4; i++) {
            float s  = acc[t][i];
            float sv = spdb[(quad * 4 + i) * 1024 + col];
            dn[i] += s * s;
            pn[i] += s * s * sv * sv;
        }
    }
#pragma unroll
    for (int m = 1; m < 16; m <<= 1)
#pragma unroll
        for (int i = 0; i < 4; i++) {
            dn[i] += __shfl_xor(dn[i], m, 64);
            pn[i] += __shfl_xor(pn[i], m, 64);
        }
    if (l16 == 0)
#pragma unroll
        for (int i = 0; i < 4; i++) {
            sred[0][wv][quad * 4 + i] = dn[i];
            sred[1][wv][quad * 4 + i] = pn[i];
        }
    __syncthreads();
    if (tid < 16) {
        float d = 0.f, p = 0.f;
        for (int w2 = 0; w2 < 4; w2++) { d += sred[0][w2][tid]; p += sred[1][w2][tid]; }
        ratio_s[tid] = sqrtf(d) / fmaxf(sqrtf(p), 1e-12f);
    }
    __syncthreads();

    // ---- pass 2: logits (overwrite acc) + row max ----
    float mx[4] = {-1e30f, -1e30f, -1e30f, -1e30f};
#pragma unroll
    for (int t = 0; t < 16; t++) {
        const int col = wv * 256 + t * 16 + l16;
#pragma unroll
        for (int i = 0; i < 4; i++) {
            float s  = acc[t][i];
            float sv = spdb[(quad * 4 + i) * 1024 + col];
            float l  = s + s * sv * ratio_s[quad * 4 + i];
            acc[t][i] = l;
            mx[i] = fmaxf(mx[i], l);
        }
    }
#pragma unroll
    for (int m = 1; m < 16; m <<= 1)
#pragma unroll
        for (int i = 0; i < 4; i++) mx[i] = fmaxf(mx[i], __shfl_xor(mx[i], m, 64));
    if (l16 == 0)
#pragma unroll
        for (int i = 0; i < 4; i++) sred[0][wv][quad * 4 + i] = mx[i];
    __syncthreads();
    if (tid < 16) {
        float m2 = -1e30f;
        for (int w2 = 0; w2 < 4; w2++) m2 = fmaxf(m2, sred[0][w2][tid]);
        rmax_s[tid] = m2;
    }
    __syncthreads();

    // ---- pass 3: exp (overwrite acc) + row sum ----
    float rs[4] = {0.f, 0.f, 0.f, 0.f};
#pragma unroll
    for (int t = 0; t < 16; t++)
#pragma unroll
        for (int i = 0; i < 4; i++) {
            float p = __expf(acc[t][i] - rmax_s[quad * 4 + i]);
            acc[t][i] = p;
            rs[i] += p;
        }
#pragma unroll
    for (int m = 1; m < 16; m <<= 1)
#pragma unroll
        for (int i = 0; i < 4; i++) rs[i] += __shfl_xor(rs[i], m, 64);
    if (l16 == 0)
#pragma unroll
        for (int i = 0; i < 4; i++) sred[0][wv][quad * 4 + i] = rs[i];
    __syncthreads();
    if (tid < 16) {
        float s = 0.f;
        for (int w2 = 0; w2 < 4; w2++) s += sred[0][w2][tid];
        float hsum = 0.f;
        for (int j = 0; j < 8; j++) hsum += hm[j];
        rinv_s[tid] = (hm[h] * 8.0f / hsum) / s;   // softmax denom + head-mask scale
    }
    __syncthreads();

    // ---- P (scaled) -> LDS in row-major, bf16 ----
#pragma unroll
    for (int t = 0; t < 16; t++) {
        const int col = wv * 256 + t * 16 + l16;
#pragma unroll
        for (int i = 0; i < 4; i++)
            sP[quad * 4 + i][col] = f2bf(acc[t][i] * rinv_s[quad * 4 + i]);
    }
    __syncthreads();

    // ---- O = P @ V : wave wv does v-dims [wv*16, wv*16+16), K-loop over 1024
    f32x4 oacc = (f32x4){0.f, 0.f, 0.f, 0.f};
    const short* vb = vt + ((size_t)bh * 64 + wv * 16 + l16) * 1024;
#pragma unroll
    for (int kkk = 0; kkk < 32; kkk++) {
        short8 pa = *(const short8*)&sP[l16][kkk * 32 + quad * 8];
        short8 vf = *(const short8*)(vb + kkk * 32 + quad * 8);
        oacc = __builtin_amdgcn_mfma_f32_16x16x32_bf16(pa, vf, oacc, 0, 0, 0);
    }
#pragma unroll
    for (int i = 0; i < 4; i++)
        o[((size_t)(b * 1024 + q0 + quad * 4 + i)) * 512 + h * 64 + wv * 16 + l16]
            = f2bf(oacc[i]);
}

// ---------------------------------------------------------------------------
// K3: out = O @ W_out + b_out   (M=8192, K=512, N=512), fp32 output
// ---------------------------------------------------------------------------
__global__ __launch_bounds__(256) void out_gemm(
    const short* __restrict__ o, const float* __restrict__ W,
    const float* __restrict__ bias, float* __restrict__ out)
{
    __shared__ short sA[64][40];
    __shared__ short sBt[64][40];

    const int tid  = threadIdx.x;
    const int wv   = tid >> 6, lane = tid & 63;
    const int quad = lane >> 4, l16 = lane & 15;
    const int m0 = blockIdx.x * 64, n0 = blockIdx.y * 64;

    f32x4 acc[4];
#pragma unroll
    for (int i = 0; i < 4; i++) acc[i] = (f32x4){0.f, 0.f, 0.f, 0.f};

    const int ar = tid >> 2, ac = (tid & 3) * 8;
    const int bk = tid >> 3, bn = (tid & 7) * 8;

    for (int ks = 0; ks < 16; ks++) {
        const int k0 = ks * 32;
        short8 av = *(const short8*)(o + (size_t)(m0 + ar) * 512 + k0 + ac);
        const float* wp = W + (size_t)(k0 + bk) * 512 + n0 + bn;
        float4 b0 = *(const float4*)wp;
        float4 b1 = *(const float4*)(wp + 4);

        __syncthreads();
        *(short8*)&sA[ar][ac] = av;
        sBt[bn + 0][bk] = f2bf(b0.x); sBt[bn + 1][bk] = f2bf(b0.y);
        sBt[bn + 2][bk] = f2bf(b0.z); sBt[bn + 3][bk] = f2bf(b0.w);
        sBt[bn + 4][bk] = f2bf(b1.x); sBt[bn + 5][bk] = f2bf(b1.y);
        sBt[bn + 6][bk] = f2bf(b1.z); sBt[bn + 7][bk] = f2bf(b1.w);
        __syncthreads();

        short8 af = *(const short8*)&sA[wv * 16 + l16][quad * 8];
#pragma unroll
        for (int ns = 0; ns < 4; ns++) {
            short8 bf = *(const short8*)&sBt[ns * 16 + l16][quad * 8];
            acc[ns] = __builtin_amdgcn_mfma_f32_16x16x32_bf16(af, bf, acc[ns], 0, 0, 0);
        }
    }

#pragma unroll
    for (int ns = 0; ns < 4; ns++) {
        const int gc = n0 + ns * 16 + l16;
        const float bv = bias[gc];
#pragma unroll
        for (int i = 0; i < 4; i++) {
            const int gm = m0 + wv * 16 + quad * 4 + i;
            out[(size_t)gm * 512 + gc] = acc[ns][i] + bv;
        }
    }
}

// ---------------------------------------------------------------------------
extern "C" void kernel_launch(void* const* d_in, const int* in_sizes, int n_in,
                              void* d_out, int out_size, void* d_ws, size_t ws_size,
                              hipStream_t stream) {
    const float* x    = (const float*)d_in[0];
    const float* spd  = (const float*)d_in[1];
    const float* hm   = (const float*)d_in[2];
    const float* Wqkv = (const float*)d_in[3];
    const float* Wout = (const float*)d_in[4];
    const float* bout = (const float*)d_in[5];
    float* out = (float*)d_out;

    char* ws = (char*)d_ws;
    short* qw  = (short*)(ws);                      // 8 MB  [bh][n][d] bf16
    short* kw  = (short*)(ws + ((size_t)8  << 20)); // 8 MB  [bh][n][d] bf16
    short* vtw = (short*)(ws + ((size_t)16 << 20)); // 8 MB  [bh][d][n] bf16
    short* ow  = (short*)(ws + ((size_t)24 << 20)); // 8 MB  [b][n][h*64+d] bf16

    qkv_gemm<<<dim3(128, 24), 256, 0, stream>>>(x, Wqkv, qw, kw, vtw);
    attn_k  <<<dim3(64, 64),  256, 0, stream>>>(qw, kw, vtw, spd, hm, ow);
    out_gemm<<<dim3(128, 8),  256, 0, stream>>>(ow, Wout, bout, out);
}